// Round 8
// baseline (26076.871 us; speedup 1.0000x reference)
//
#include <hip/hip_runtime.h>
#include <stdint.h>
#include <stddef.h>

#define T_SEQ 8192
#define HDIM  2048
#define NB    256
#define NT    512

typedef unsigned long long u64;
typedef unsigned int u32x4 __attribute__((ext_vector_type(4)));

// workspace layout (bytes):
//   [0,4096)       : 256 per-WG flags, one int per 16B (tail barriers only)
//   [4096,36864)   : hbt u64[2][2048] — tagged h: hi32 = step tag, lo32 = float bits
//   [36864,69632)  : feat float[8192]
//   [69632,77824)  : hid  float[2048]
#define WS_ZERO_DWORDS 9216   // 36864 bytes

__global__ void init_ws_kernel(uint32_t* ws) {
    int i = blockIdx.x * blockDim.x + threadIdx.x;
    if (i < WS_ZERO_DWORDS) ws[i] = 0u;
}

__device__ __forceinline__ float sigm(float xv) { return 1.0f / (1.0f + expf(-xv)); }

// amdgpu_waves_per_eu(2,2): pins occupancy target to 2 waves/EU so the
// 128-VGPR weight array stays in registers (no scratch spill).
__global__ void __launch_bounds__(NT)
__attribute__((amdgpu_waves_per_eu(2, 2)))
policy_persistent(
    const float* __restrict__ x,      // (8192,3)
    const float* __restrict__ ldist,  // scalar
    const float* __restrict__ lhead,  // scalar
    const float* __restrict__ W_ih,   // (8192,3)
    const float* __restrict__ W_hh,   // (8192,2048)
    const float* __restrict__ b_ih,   // (8192)
    const float* __restrict__ b_hh,   // (8192)
    const float* __restrict__ W1,     // (2048,8192)
    const float* __restrict__ b1,     // (2048)
    const float* __restrict__ W2,     // (4,2048)
    const float* __restrict__ b2,     // (4)
    float* __restrict__ out,          // (4)
    int*   __restrict__ flags,        // 256 flags, stride 4 ints (16B)
    u64*   __restrict__ hbt,          // 2*2048 tagged h
    float* __restrict__ feat,         // 8192
    float* __restrict__ hid)          // 2048
{
    const int w    = blockIdx.x;
    const int tid  = threadIdx.x;
    const int v    = tid >> 6;             // wave 0..7
    const int lane = tid & 63;
    const int r    = v * 4 + (lane >> 4);  // row within WG block, 0..31
    const int g    = lane & 15;            // 128-col chunk, 0..15
    const int q    = r >> 3;               // gate (i,f,g,o)
    const int p    = r & 7;                // h offset within this WG's 8

    __shared__ float4 h_lds4[16 * 33];   // chunk c at float4 index c*33 (pad 1)
    __shared__ float  gates_lds[128];
    __shared__ float  c_lds[8];
    __shared__ float  red_lds[8];
    __shared__ float  feat_lds[4 * HDIM]; // 32KB, MLP phase

    const int row = q * HDIM + 8 * w + p;  // global gate row in [0,8192)

    // ---- load this lane's 128 W_hh weights into registers (32 float4) ----
    float4 wreg[32];
    {
        const float4* wp = (const float4*)(W_hh + (size_t)row * HDIM) + g * 32;
#pragma unroll
        for (int i = 0; i < 32; ++i) {
            wreg[i] = wp[i];
            asm volatile("" : "+v"(wreg[i].x), "+v"(wreg[i].y),
                              "+v"(wreg[i].z), "+v"(wreg[i].w));
        }
    }
    const float brow = b_ih[row] + b_hh[row];
    const float wih0 = W_ih[row * 3 + 0];
    const float wih1 = W_ih[row * 3 + 1];
    const float wih2 = W_ih[row * 3 + 2];
    if (tid < 8) c_lds[tid] = 0.0f;

    // ---- sequential recurrence + action step (t == T_SEQ) ----
    for (int t = 0; t <= T_SEQ; ++t) {
        // prefetch x[t] BEFORE the poll — independent of h
        float xt0 = 0.f, xt1 = 0.f, xt2 = 0.f;
        if (t < T_SEQ) { xt0 = x[3 * t]; xt1 = x[3 * t + 1]; xt2 = x[3 * t + 2]; }

        // SCOUT phase (R4 protocol, single change: WAVE 1 scouts).
        // Wave 0 serialized cell->publish->scout in R4; wave 1 was idle at B1.
        // Moving the scout to wave 1 starts detection DURING wave 0's cell
        // math + publish (concurrent, same traffic). Wave 1 polls the 256
        // line-tags with BYPASS loads, 4 lines/lane, blocking round + sleep
        // backoff (R4-proven traffic level; R7 showed faster sampling is a
        // net loss via MALL congestion).
        if (v == 1) {
            const u64* base = hbt + (size_t)((t + 1) & 1) * HDIM;
            const u64* p0 = base + 8 * (size_t)lane;  // line `lane`
            const u64* p1 = p0 + 512;                 // line lane+64
            const u64* p2 = p0 + 1024;                // line lane+128
            const u64* p3 = p0 + 1536;                // line lane+192
            const uint32_t want = (uint32_t)t;
            for (;;) {
                u64 a0, a1, a2, a3;
                asm volatile(
                    "global_load_dwordx2 %0, %4, off sc0 sc1\n\t"
                    "global_load_dwordx2 %1, %5, off sc0 sc1\n\t"
                    "global_load_dwordx2 %2, %6, off sc0 sc1\n\t"
                    "global_load_dwordx2 %3, %7, off sc0 sc1\n\t"
                    "s_waitcnt vmcnt(0)"
                    : "=&v"(a0), "=&v"(a1), "=&v"(a2), "=&v"(a3)
                    : "v"(p0), "v"(p1), "v"(p2), "v"(p3)
                    : "memory");
                if ((uint32_t)(a0 >> 32) == want && (uint32_t)(a1 >> 32) == want &&
                    (uint32_t)(a2 >> 32) == want && (uint32_t)(a3 >> 32) == want)
                    break;
                __builtin_amdgcn_s_sleep(1);
            }
        }
        __syncthreads();

        // BULK phase: one 32B bypass load per thread + tag verify (normally
        // passes first try — the loop is the safety net if the producer's
        // 64B write ever splits into sectors).
        {
            const u64* hp = hbt + (size_t)((t + 1) & 1) * HDIM + (size_t)tid * 4;
            const uint32_t want = (uint32_t)t;
            u32x4 b0, b1;
            for (;;) {
                asm volatile(
                    "global_load_dwordx4 %0, %2, off sc0 sc1\n\t"
                    "global_load_dwordx4 %1, %2, off offset:16 sc0 sc1\n\t"
                    "s_waitcnt vmcnt(0)"
                    : "=&v"(b0), "=&v"(b1)
                    : "v"(hp)
                    : "memory");
                if (b0.y == want && b0.w == want && b1.y == want && b1.w == want)
                    break;
                __builtin_amdgcn_s_sleep(1);
            }
            h_lds4[(tid >> 5) * 33 + (tid & 31)] =
                make_float4(__uint_as_float(b0.x), __uint_as_float(b0.z),
                            __uint_as_float(b1.x), __uint_as_float(b1.z));
        }
        __syncthreads();

        // partial GEMV from register weights (identical arithmetic order)
        float acc = 0.0f;
        {
            const float4* hb = &h_lds4[g * 33];
#pragma unroll
            for (int i = 0; i < 32; ++i) {
                float4 hv = hb[i];
                float4 wv = wreg[i];
                acc = fmaf(wv.x, hv.x, acc); acc = fmaf(wv.y, hv.y, acc);
                acc = fmaf(wv.z, hv.z, acc); acc = fmaf(wv.w, hv.w, acc);
            }
        }
        // reduce over the 16 col-chunks (lane bits 0..3)
        acc += __shfl_xor(acc, 1, 64);
        acc += __shfl_xor(acc, 2, 64);
        acc += __shfl_xor(acc, 4, 64);
        acc += __shfl_xor(acc, 8, 64);

        if (t < T_SEQ) {
            if (g == 0) {
                float xg = wih0 * xt0 + wih1 * xt1 + wih2 * xt2;
                gates_lds[q * 8 + p] = acc + brow + xg;
            }
            __syncthreads();
            if (v == 0 && lane < 8) {
                float ig = gates_lds[lane],      fg = gates_lds[8 + lane];
                float gg = gates_lds[16 + lane], og = gates_lds[24 + lane];
                float c0 = c_lds[lane];
                float cn = sigm(fg) * c0 + sigm(ig) * tanhf(gg);
                float hn = sigm(og) * tanhf(cn);
                c_lds[lane] = cn;
                // COALESCED tagged publish: 8 contiguous lanes, one 64B txn
                u64 pk = ((u64)(uint32_t)(t + 1) << 32) | (u64)__float_as_uint(hn);
                __hip_atomic_store(hbt + (size_t)(t & 1) * HDIM + 8 * w + lane, pk,
                                   __ATOMIC_RELAXED, __HIP_MEMORY_SCOPE_AGENT);
            }
            // no fence, no flag: tag travels with the data; wave 1 is already
            // scouting the next step's tags while this store drains.
        } else {
            // 4 batched action rollouts from (h_n, c_n); W_hh@h_n already in acc
            const float ld0 = *ldist, lh0 = *lhead;
            if (g == 0) {
#pragma unroll
                for (int a = 0; a < 4; ++a) {
                    float xg = wih0 * ld0 + wih1 * lh0 + wih2 * (float)a;
                    gates_lds[a * 32 + q * 8 + p] = acc + brow + xg;
                }
            }
            __syncthreads();
            if (v == 0) {
                if (lane < 8) {
                    float c0 = c_lds[lane];
#pragma unroll
                    for (int a = 0; a < 4; ++a) {
                        float ig = gates_lds[a * 32 + lane];
                        float fg = gates_lds[a * 32 + 8 + lane];
                        float gg = gates_lds[a * 32 + 16 + lane];
                        float og = gates_lds[a * 32 + 24 + lane];
                        float cn = sigm(fg) * c0 + sigm(ig) * tanhf(gg);
                        float hn = sigm(og) * tanhf(cn);
                        __hip_atomic_store(&feat[a * HDIM + 8 * w + lane], hn,
                                           __ATOMIC_RELAXED, __HIP_MEMORY_SCOPE_AGENT);
                    }
                }
                __threadfence();
                if (lane == 0)
                    __hip_atomic_store(&flags[w * 4], 1, __ATOMIC_RELAXED,
                                       __HIP_MEMORY_SCOPE_AGENT);
            }
        }
    }

    // ---- MLP layer 1: hid = relu(W1 @ feat + b1), 8 rows per WG ----
    if (tid < 256) {
        while (__hip_atomic_load(&flags[tid * 4], __ATOMIC_RELAXED,
                                 __HIP_MEMORY_SCOPE_AGENT) < 1)
            __builtin_amdgcn_s_sleep(1);
    }
    __syncthreads();
    {
        const u64* f64 = (const u64*)feat;
        u64* fl64 = (u64*)feat_lds;
#pragma unroll
        for (int k = 0; k < 8; ++k) {
            u64 a = __hip_atomic_load(f64 + k * NT + tid, __ATOMIC_RELAXED,
                                      __HIP_MEMORY_SCOPE_AGENT);
            fl64[k * NT + tid] = a;
        }
    }
    __syncthreads();
    const float4* flds4 = (const float4*)feat_lds;
    for (int rr = 0; rr < 8; ++rr) {
        const int hrow = 8 * w + rr;
        const float4* Wrow4 = (const float4*)(W1 + (size_t)hrow * 4 * HDIM);
        float pacc = 0.0f;
#pragma unroll
        for (int s = 0; s < 4; ++s) {
            int idx = s * NT + tid;
            float4 wv = Wrow4[idx];
            float4 fv = flds4[idx];
            pacc = fmaf(wv.x, fv.x, pacc); pacc = fmaf(wv.y, fv.y, pacc);
            pacc = fmaf(wv.z, fv.z, pacc); pacc = fmaf(wv.w, fv.w, pacc);
        }
#pragma unroll
        for (int m = 1; m < 64; m <<= 1) pacc += __shfl_xor(pacc, m, 64);
        if (lane == 0) red_lds[v] = pacc;
        __syncthreads();
        if (tid == 0) {
            float s = b1[hrow];
#pragma unroll
            for (int k = 0; k < 8; ++k) s += red_lds[k];
            __hip_atomic_store(&hid[hrow], fmaxf(s, 0.0f), __ATOMIC_RELAXED,
                               __HIP_MEMORY_SCOPE_AGENT);
        }
        __syncthreads();
    }
    __threadfence();
    if (tid == 0)
        __hip_atomic_store(&flags[w * 4], 2, __ATOMIC_RELAXED,
                           __HIP_MEMORY_SCOPE_AGENT);

    // ---- output layer: WG 0 only ----
    if (w == 0) {
        if (tid < 256) {
            while (__hip_atomic_load(&flags[tid * 4], __ATOMIC_RELAXED,
                                     __HIP_MEMORY_SCOPE_AGENT) < 2)
                __builtin_amdgcn_s_sleep(1);
        }
        __syncthreads();
        float hv4[4];
        {
            const u64* h64 = (const u64*)hid;
            u64 a0 = __hip_atomic_load(h64 + 2 * tid,     __ATOMIC_RELAXED,
                                       __HIP_MEMORY_SCOPE_AGENT);
            u64 a1 = __hip_atomic_load(h64 + 2 * tid + 1, __ATOMIC_RELAXED,
                                       __HIP_MEMORY_SCOPE_AGENT);
            float2 f0 = *(float2*)&a0;
            float2 f1 = *(float2*)&a1;
            hv4[0] = f0.x; hv4[1] = f0.y; hv4[2] = f1.x; hv4[3] = f1.y;
        }
#pragma unroll
        for (int o = 0; o < 4; ++o) {
            float pv = 0.0f;
#pragma unroll
            for (int k = 0; k < 4; ++k)
                pv = fmaf(W2[o * HDIM + tid * 4 + k], hv4[k], pv);
#pragma unroll
            for (int m = 1; m < 64; m <<= 1) pv += __shfl_xor(pv, m, 64);
            if (lane == 0) red_lds[v] = pv;
            __syncthreads();
            if (tid == 0) {
                float s = b2[o];
#pragma unroll
                for (int k = 0; k < 8; ++k) s += red_lds[k];
                out[o] = s;
            }
            __syncthreads();
        }
    }
}

extern "C" void kernel_launch(void* const* d_in, const int* in_sizes, int n_in,
                              void* d_out, int out_size, void* d_ws, size_t ws_size,
                              hipStream_t stream) {
    const float* x     = (const float*)d_in[0];
    const float* ldist = (const float*)d_in[1];
    const float* lhead = (const float*)d_in[2];
    const float* W_ih  = (const float*)d_in[3];
    const float* W_hh  = (const float*)d_in[4];
    const float* b_ih  = (const float*)d_in[5];
    const float* b_hh  = (const float*)d_in[6];
    const float* W1    = (const float*)d_in[7];
    const float* b1    = (const float*)d_in[8];
    const float* W2    = (const float*)d_in[9];
    const float* b2    = (const float*)d_in[10];
    float* out = (float*)d_out;

    uint8_t* wsb = (uint8_t*)d_ws;
    int*   flags = (int*)wsb;
    u64*   hbt   = (u64*)(wsb + 4096);
    float* feat  = (float*)(wsb + 36864);
    float* hid   = (float*)(wsb + 69632);

    // zero flags + tagged h buffers (ws is poisoned 0xAA before every launch)
    hipLaunchKernelGGL(init_ws_kernel, dim3(36), dim3(256), 0, stream, (uint32_t*)d_ws);

    void* args[] = {
        (void*)&x, (void*)&ldist, (void*)&lhead, (void*)&W_ih, (void*)&W_hh,
        (void*)&b_ih, (void*)&b_hh, (void*)&W1, (void*)&b1, (void*)&W2, (void*)&b2,
        (void*)&out, (void*)&flags, (void*)&hbt, (void*)&feat, (void*)&hid
    };
    hipError_t e = hipLaunchCooperativeKernel((void*)policy_persistent,
                                              dim3(NB), dim3(NT), args, 0, stream);
    if (e != hipSuccess) {
        // fallback: normal launch — 8 waves x 256 VGPRs fills the CU register
        // file, so 256 WGs on 256 CUs are co-resident anyway.
        hipLaunchKernelGGL(policy_persistent, dim3(NB), dim3(NT), 0, stream,
                           x, ldist, lhead, W_ih, W_hh, b_ih, b_hh, W1, b1, W2, b2,
                           out, flags, hbt, feat, hid);
    }
}

// Round 9
// 23850.990 us; speedup vs baseline: 1.0933x; 1.0933x over previous
//
#include <hip/hip_runtime.h>
#include <stdint.h>
#include <stddef.h>

#define T_SEQ 8192
#define HDIM  2048
#define NB    256
#define NT    512

typedef unsigned long long u64;
typedef unsigned int u32x4 __attribute__((ext_vector_type(4)));

// workspace layout (bytes), ncpy = 8 (or 1 if ws too small):
//   [0,4096)                  : 256 per-WG flags, one int per 16B (tail barriers)
//   [4096, 4096+ncpy*32768)   : hbt u64[ncpy][2][2048] — REPLICATED tagged h
//                               (hi32 = step tag, lo32 = float bits)
//   [+0,+32768)               : feat float[8192]
//   [+32768,+40960)           : hid  float[2048]
// Replication spreads the per-step all-to-all read burst (4MB of the same
// 16KB) over 8x the cache lines -> 8x less same-line slice serialization.

__global__ void init_ws_kernel(uint32_t* ws, int ndw) {
    int i = blockIdx.x * blockDim.x + threadIdx.x;
    if (i < ndw) ws[i] = 0u;
}

__device__ __forceinline__ float sigm(float xv) { return 1.0f / (1.0f + expf(-xv)); }

// amdgpu_waves_per_eu(2,2): pins occupancy target to 2 waves/EU so the
// 128-VGPR weight array stays in registers (no scratch spill).
__global__ void __launch_bounds__(NT)
__attribute__((amdgpu_waves_per_eu(2, 2)))
policy_persistent(
    const float* __restrict__ x,      // (8192,3)
    const float* __restrict__ ldist,  // scalar
    const float* __restrict__ lhead,  // scalar
    const float* __restrict__ W_ih,   // (8192,3)
    const float* __restrict__ W_hh,   // (8192,2048)
    const float* __restrict__ b_ih,   // (8192)
    const float* __restrict__ b_hh,   // (8192)
    const float* __restrict__ W1,     // (2048,8192)
    const float* __restrict__ b1,     // (2048)
    const float* __restrict__ W2,     // (4,2048)
    const float* __restrict__ b2,     // (4)
    float* __restrict__ out,          // (4)
    int*   __restrict__ flags,        // 256 flags, stride 4 ints (16B)
    u64*   __restrict__ hbt,          // ncpy * 2 * 2048 tagged h
    float* __restrict__ feat,         // 8192
    float* __restrict__ hid,          // 2048
    int ncpy)                         // 8 (or 1 fallback == exact R4)
{
    const int w    = blockIdx.x;
    const int tid  = threadIdx.x;
    const int v    = tid >> 6;             // wave 0..7
    const int lane = tid & 63;
    const int r    = v * 4 + (lane >> 4);  // row within WG block, 0..31
    const int g    = lane & 15;            // 128-col chunk, 0..15
    const int q    = r >> 3;               // gate (i,f,g,o)
    const int p    = r & 7;                // h offset within this WG's 8

    __shared__ float4 h_lds4[16 * 33];   // chunk c at float4 index c*33 (pad 1)
    __shared__ float  gates_lds[128];
    __shared__ float  c_lds[8];
    __shared__ float  red_lds[8];
    __shared__ float  feat_lds[4 * HDIM]; // 32KB, MLP phase

    const int row = q * HDIM + 8 * w + p;  // global gate row in [0,8192)

    // this WG's READ copy (spreads consumers across the ncpy replicas)
    u64* const hb = hbt + (size_t)(w & (ncpy - 1)) * 2 * HDIM;

    // ---- load this lane's 128 W_hh weights into registers (32 float4) ----
    float4 wreg[32];
    {
        const float4* wp = (const float4*)(W_hh + (size_t)row * HDIM) + g * 32;
#pragma unroll
        for (int i = 0; i < 32; ++i) {
            wreg[i] = wp[i];
            asm volatile("" : "+v"(wreg[i].x), "+v"(wreg[i].y),
                              "+v"(wreg[i].z), "+v"(wreg[i].w));
        }
    }
    const float brow = b_ih[row] + b_hh[row];
    const float wih0 = W_ih[row * 3 + 0];
    const float wih1 = W_ih[row * 3 + 1];
    const float wih2 = W_ih[row * 3 + 2];
    if (tid < 8) c_lds[tid] = 0.0f;

    // ---- sequential recurrence + action step (t == T_SEQ) ----
    for (int t = 0; t <= T_SEQ; ++t) {
        // prefetch x[t] BEFORE the poll — independent of h
        float xt0 = 0.f, xt1 = 0.f, xt2 = 0.f;
        if (t < T_SEQ) { xt0 = x[3 * t]; xt1 = x[3 * t + 1]; xt2 = x[3 * t + 2]; }

        // SCOUT phase (R4 protocol, unchanged): wave 0 polls the 256
        // line-tags of ITS copy with narrow bypass loads, 4 lines/lane,
        // blocking round + sleep backoff.
        if (v == 0) {
            const u64* base = hb + (size_t)((t + 1) & 1) * HDIM;
            const u64* p0 = base + 8 * (size_t)lane;  // line `lane`
            const u64* p1 = p0 + 512;                 // line lane+64
            const u64* p2 = p0 + 1024;                // line lane+128
            const u64* p3 = p0 + 1536;                // line lane+192
            const uint32_t want = (uint32_t)t;
            for (;;) {
                u64 a0, a1, a2, a3;
                asm volatile(
                    "global_load_dwordx2 %0, %4, off sc0 sc1\n\t"
                    "global_load_dwordx2 %1, %5, off sc0 sc1\n\t"
                    "global_load_dwordx2 %2, %6, off sc0 sc1\n\t"
                    "global_load_dwordx2 %3, %7, off sc0 sc1\n\t"
                    "s_waitcnt vmcnt(0)"
                    : "=&v"(a0), "=&v"(a1), "=&v"(a2), "=&v"(a3)
                    : "v"(p0), "v"(p1), "v"(p2), "v"(p3)
                    : "memory");
                if ((uint32_t)(a0 >> 32) == want && (uint32_t)(a1 >> 32) == want &&
                    (uint32_t)(a2 >> 32) == want && (uint32_t)(a3 >> 32) == want)
                    break;
                __builtin_amdgcn_s_sleep(1);
            }
        }
        __syncthreads();

        // BULK phase (unchanged except copy base): one 32B bypass load per
        // thread + per-word tag verify (tear safety net).
        {
            const u64* hp = hb + (size_t)((t + 1) & 1) * HDIM + (size_t)tid * 4;
            const uint32_t want = (uint32_t)t;
            u32x4 b0, b1;
            for (;;) {
                asm volatile(
                    "global_load_dwordx4 %0, %2, off sc0 sc1\n\t"
                    "global_load_dwordx4 %1, %2, off offset:16 sc0 sc1\n\t"
                    "s_waitcnt vmcnt(0)"
                    : "=&v"(b0), "=&v"(b1)
                    : "v"(hp)
                    : "memory");
                if (b0.y == want && b0.w == want && b1.y == want && b1.w == want)
                    break;
                __builtin_amdgcn_s_sleep(1);
            }
            h_lds4[(tid >> 5) * 33 + (tid & 31)] =
                make_float4(__uint_as_float(b0.x), __uint_as_float(b0.z),
                            __uint_as_float(b1.x), __uint_as_float(b1.z));
        }
        __syncthreads();

        // partial GEMV from register weights (identical arithmetic order)
        float acc = 0.0f;
        {
            const float4* hb4 = &h_lds4[g * 33];
#pragma unroll
            for (int i = 0; i < 32; ++i) {
                float4 hv = hb4[i];
                float4 wv = wreg[i];
                acc = fmaf(wv.x, hv.x, acc); acc = fmaf(wv.y, hv.y, acc);
                acc = fmaf(wv.z, hv.z, acc); acc = fmaf(wv.w, hv.w, acc);
            }
        }
        // reduce over the 16 col-chunks (lane bits 0..3)
        acc += __shfl_xor(acc, 1, 64);
        acc += __shfl_xor(acc, 2, 64);
        acc += __shfl_xor(acc, 4, 64);
        acc += __shfl_xor(acc, 8, 64);

        if (t < T_SEQ) {
            if (g == 0) {
                float xg = wih0 * xt0 + wih1 * xt1 + wih2 * xt2;
                gates_lds[q * 8 + p] = acc + brow + xg;
            }
            __syncthreads();
            if (v == 0) {
                float hn = 0.0f;
                if (lane < 8) {
                    float ig = gates_lds[lane],      fg = gates_lds[8 + lane];
                    float gg = gates_lds[16 + lane], og = gates_lds[24 + lane];
                    float c0 = c_lds[lane];
                    float cn = sigm(fg) * c0 + sigm(ig) * tanhf(gg);
                    hn = sigm(og) * tanhf(cn);
                    c_lds[lane] = cn;
                }
                // REPLICATED coalesced publish: lane j stores value (j&7) to
                // copy (j>>3) — one wave-store covers all 8 copies, 8
                // coalesced 64B lines. ncpy==1 -> lanes<8, exactly R4.
                float hj = __shfl(hn, lane & 7, 64);
                if (lane < 8 * ncpy) {
                    u64 pk = ((u64)(uint32_t)(t + 1) << 32) | (u64)__float_as_uint(hj);
                    __hip_atomic_store(hbt + (size_t)(lane >> 3) * 2 * HDIM
                                           + (size_t)(t & 1) * HDIM + 8 * w + (lane & 7),
                                       pk, __ATOMIC_RELAXED, __HIP_MEMORY_SCOPE_AGENT);
                }
            }
            // no fence, no flag: tag travels with the data
        } else {
            // 4 batched action rollouts from (h_n, c_n); W_hh@h_n already in acc
            const float ld0 = *ldist, lh0 = *lhead;
            if (g == 0) {
#pragma unroll
                for (int a = 0; a < 4; ++a) {
                    float xg = wih0 * ld0 + wih1 * lh0 + wih2 * (float)a;
                    gates_lds[a * 32 + q * 8 + p] = acc + brow + xg;
                }
            }
            __syncthreads();
            if (v == 0) {
                if (lane < 8) {
                    float c0 = c_lds[lane];
#pragma unroll
                    for (int a = 0; a < 4; ++a) {
                        float ig = gates_lds[a * 32 + lane];
                        float fg = gates_lds[a * 32 + 8 + lane];
                        float gg = gates_lds[a * 32 + 16 + lane];
                        float og = gates_lds[a * 32 + 24 + lane];
                        float cn = sigm(fg) * c0 + sigm(ig) * tanhf(gg);
                        float hn = sigm(og) * tanhf(cn);
                        __hip_atomic_store(&feat[a * HDIM + 8 * w + lane], hn,
                                           __ATOMIC_RELAXED, __HIP_MEMORY_SCOPE_AGENT);
                    }
                }
                __threadfence();
                if (lane == 0)
                    __hip_atomic_store(&flags[w * 4], 1, __ATOMIC_RELAXED,
                                       __HIP_MEMORY_SCOPE_AGENT);
            }
        }
    }

    // ---- MLP layer 1: hid = relu(W1 @ feat + b1), 8 rows per WG ----
    if (tid < 256) {
        while (__hip_atomic_load(&flags[tid * 4], __ATOMIC_RELAXED,
                                 __HIP_MEMORY_SCOPE_AGENT) < 1)
            __builtin_amdgcn_s_sleep(1);
    }
    __syncthreads();
    {
        const u64* f64 = (const u64*)feat;
        u64* fl64 = (u64*)feat_lds;
#pragma unroll
        for (int k = 0; k < 8; ++k) {
            u64 a = __hip_atomic_load(f64 + k * NT + tid, __ATOMIC_RELAXED,
                                      __HIP_MEMORY_SCOPE_AGENT);
            fl64[k * NT + tid] = a;
        }
    }
    __syncthreads();
    const float4* flds4 = (const float4*)feat_lds;
    for (int rr = 0; rr < 8; ++rr) {
        const int hrow = 8 * w + rr;
        const float4* Wrow4 = (const float4*)(W1 + (size_t)hrow * 4 * HDIM);
        float pacc = 0.0f;
#pragma unroll
        for (int s = 0; s < 4; ++s) {
            int idx = s * NT + tid;
            float4 wv = Wrow4[idx];
            float4 fv = flds4[idx];
            pacc = fmaf(wv.x, fv.x, pacc); pacc = fmaf(wv.y, fv.y, pacc);
            pacc = fmaf(wv.z, fv.z, pacc); pacc = fmaf(wv.w, fv.w, pacc);
        }
#pragma unroll
        for (int m = 1; m < 64; m <<= 1) pacc += __shfl_xor(pacc, m, 64);
        if (lane == 0) red_lds[v] = pacc;
        __syncthreads();
        if (tid == 0) {
            float s = b1[hrow];
#pragma unroll
            for (int k = 0; k < 8; ++k) s += red_lds[k];
            __hip_atomic_store(&hid[hrow], fmaxf(s, 0.0f), __ATOMIC_RELAXED,
                               __HIP_MEMORY_SCOPE_AGENT);
        }
        __syncthreads();
    }
    __threadfence();
    if (tid == 0)
        __hip_atomic_store(&flags[w * 4], 2, __ATOMIC_RELAXED,
                           __HIP_MEMORY_SCOPE_AGENT);

    // ---- output layer: WG 0 only ----
    if (w == 0) {
        if (tid < 256) {
            while (__hip_atomic_load(&flags[tid * 4], __ATOMIC_RELAXED,
                                     __HIP_MEMORY_SCOPE_AGENT) < 2)
                __builtin_amdgcn_s_sleep(1);
        }
        __syncthreads();
        float hv4[4];
        {
            const u64* h64 = (const u64*)hid;
            u64 a0 = __hip_atomic_load(h64 + 2 * tid,     __ATOMIC_RELAXED,
                                       __HIP_MEMORY_SCOPE_AGENT);
            u64 a1 = __hip_atomic_load(h64 + 2 * tid + 1, __ATOMIC_RELAXED,
                                       __HIP_MEMORY_SCOPE_AGENT);
            float2 f0 = *(float2*)&a0;
            float2 f1 = *(float2*)&a1;
            hv4[0] = f0.x; hv4[1] = f0.y; hv4[2] = f1.x; hv4[3] = f1.y;
        }
#pragma unroll
        for (int o = 0; o < 4; ++o) {
            float pv = 0.0f;
#pragma unroll
            for (int k = 0; k < 4; ++k)
                pv = fmaf(W2[o * HDIM + tid * 4 + k], hv4[k], pv);
#pragma unroll
            for (int m = 1; m < 64; m <<= 1) pv += __shfl_xor(pv, m, 64);
            if (lane == 0) red_lds[v] = pv;
            __syncthreads();
            if (tid == 0) {
                float s = b2[o];
#pragma unroll
                for (int k = 0; k < 8; ++k) s += red_lds[k];
                out[o] = s;
            }
            __syncthreads();
        }
    }
}

extern "C" void kernel_launch(void* const* d_in, const int* in_sizes, int n_in,
                              void* d_out, int out_size, void* d_ws, size_t ws_size,
                              hipStream_t stream) {
    const float* x     = (const float*)d_in[0];
    const float* ldist = (const float*)d_in[1];
    const float* lhead = (const float*)d_in[2];
    const float* W_ih  = (const float*)d_in[3];
    const float* W_hh  = (const float*)d_in[4];
    const float* b_ih  = (const float*)d_in[5];
    const float* b_hh  = (const float*)d_in[6];
    const float* W1    = (const float*)d_in[7];
    const float* b1    = (const float*)d_in[8];
    const float* W2    = (const float*)d_in[9];
    const float* b2    = (const float*)d_in[10];
    float* out = (float*)d_out;

    uint8_t* wsb = (uint8_t*)d_ws;
    // 8 replicas need 4096 + 8*32768 + 32768 + 8192 = 307200 B; else ncpy=1
    int ncpy = (ws_size >= (size_t)307200) ? 8 : 1;
    int*   flags = (int*)wsb;
    u64*   hbt   = (u64*)(wsb + 4096);
    float* feat  = (float*)(wsb + 4096 + (size_t)ncpy * 32768);
    float* hid   = (float*)(wsb + 4096 + (size_t)ncpy * 32768 + 32768);

    // zero flags + ALL hbt replicas (ws is poisoned 0xAA before every launch)
    int zero_dwords = (4096 + ncpy * 32768) / 4;
    hipLaunchKernelGGL(init_ws_kernel, dim3((zero_dwords + 255) / 256), dim3(256),
                       0, stream, (uint32_t*)d_ws, zero_dwords);

    void* args[] = {
        (void*)&x, (void*)&ldist, (void*)&lhead, (void*)&W_ih, (void*)&W_hh,
        (void*)&b_ih, (void*)&b_hh, (void*)&W1, (void*)&b1, (void*)&W2, (void*)&b2,
        (void*)&out, (void*)&flags, (void*)&hbt, (void*)&feat, (void*)&hid,
        (void*)&ncpy
    };
    hipError_t e = hipLaunchCooperativeKernel((void*)policy_persistent,
                                              dim3(NB), dim3(NT), args, 0, stream);
    if (e != hipSuccess) {
        // fallback: normal launch — 8 waves x 256 VGPRs fills the CU register
        // file, so 256 WGs on 256 CUs are co-resident anyway.
        hipLaunchKernelGGL(policy_persistent, dim3(NB), dim3(NT), 0, stream,
                           x, ldist, lhead, W_ih, W_hh, b_ih, b_hh, W1, b1, W2, b2,
                           out, flags, hbt, feat, hid, ncpy);
    }
}